// Round 4
// baseline (542.703 us; speedup 1.0000x reference)
//
#include <hip/hip_runtime.h>

typedef unsigned short ushort_t;
typedef __bf16 bf16x8 __attribute__((ext_vector_type(8)));
typedef float f32x4 __attribute__((ext_vector_type(4)));

// sizes (fixed by the problem)
#define NB 8
#define BB 2
#define TT 2048
#define DD 2048
#define FF 8192
#define MM (BB * TT)          // 4096 rows
#define BTD ((size_t)BB * TT * DD)   // 8388608

__device__ __forceinline__ unsigned short f2bf(float f) {
  unsigned int u = __float_as_uint(f);
  u += 0x7FFFu + ((u >> 16) & 1u);
  return (unsigned short)(u >> 16);
}

__device__ __forceinline__ float gelu_tanh(float x) {
  float u = 0.7978845608028654f * (x + 0.044715f * x * x * x);
  float e = __expf(2.0f * u);
  float th = 1.0f - 2.0f / (e + 1.0f);   // robust tanh(u), e=inf -> 1
  return 0.5f * x * (1.0f + th);
}

template <int N>
__device__ __forceinline__ void wait_vmcnt() {
  if constexpr (N == 0) asm volatile("s_waitcnt vmcnt(0)" ::: "memory");
  else if constexpr (N == 2) asm volatile("s_waitcnt vmcnt(2)" ::: "memory");
  else if constexpr (N == 4) asm volatile("s_waitcnt vmcnt(4)" ::: "memory");
  else if constexpr (N == 6) asm volatile("s_waitcnt vmcnt(6)" ::: "memory");
}

#define ASYNC_COPY16(gp, lp)                                                   \
  __builtin_amdgcn_global_load_lds(                                            \
      (__attribute__((address_space(1))) void*)(gp),                           \
      (__attribute__((address_space(3))) void*)(lp), 16, 0, 0)

// ---------------------------------------------------------------------------
// fp32 (R x C) -> bf16 transposed (C x R)
__global__ __launch_bounds__(256) void transpose_conv(
    const float* __restrict__ in, ushort_t* __restrict__ out, int R, int C) {
  __shared__ float tile[32][33];
  const int tx = threadIdx.x & 31, ty = threadIdx.x >> 5;
  const int r0 = blockIdx.y * 32, c0 = blockIdx.x * 32;
#pragma unroll
  for (int i = 0; i < 32; i += 8)
    tile[ty + i][tx] = in[(size_t)(r0 + ty + i) * C + (c0 + tx)];
  __syncthreads();
#pragma unroll
  for (int i = 0; i < 32; i += 8)
    out[(size_t)(c0 + ty + i) * R + (r0 + tx)] = f2bf(tile[tx][ty + i]);
}

// ---------------------------------------------------------------------------
// Fused block-attention: one block per (b,t) row.
__global__ __launch_bounds__(256) void attn_fuse(
    const float* __restrict__ blocks, const float* __restrict__ partial,
    const float* __restrict__ proj_w, const float* __restrict__ norm_scale,
    float* __restrict__ h_out, ushort_t* __restrict__ h_bf) {
  const int t = threadIdx.x;
  const int bt = blockIdx.x;
  const size_t rowoff = (size_t)bt * DD;
  const int d0 = t * 4;

  float w[8];
  {
    float4 ns = *(const float4*)(norm_scale + d0);
    float4 pw = *(const float4*)(proj_w + d0);
    w[0] = ns.x * pw.x; w[1] = ns.y * pw.y; w[2] = ns.z * pw.z; w[3] = ns.w * pw.w;
    ns = *(const float4*)(norm_scale + 1024 + d0);
    pw = *(const float4*)(proj_w + 1024 + d0);
    w[4] = ns.x * pw.x; w[5] = ns.y * pw.y; w[6] = ns.z * pw.z; w[7] = ns.w * pw.w;
  }

  float ss[9], dt[9];
#pragma unroll
  for (int n = 0; n < 9; ++n) {
    const float* rp = (n < 8) ? (blocks + (size_t)n * BTD + rowoff)
                              : (partial + rowoff);
    float4 v0 = *(const float4*)(rp + d0);
    float4 v1 = *(const float4*)(rp + 1024 + d0);
    ss[n] = v0.x * v0.x + v0.y * v0.y + v0.z * v0.z + v0.w * v0.w +
            v1.x * v1.x + v1.y * v1.y + v1.z * v1.z + v1.w * v1.w;
    dt[n] = v0.x * w[0] + v0.y * w[1] + v0.z * w[2] + v0.w * w[3] +
            v1.x * w[4] + v1.y * w[5] + v1.z * w[6] + v1.w * w[7];
  }

  __shared__ float red[2][9][4];
  const int lane = t & 63, wv = t >> 6;
#pragma unroll
  for (int n = 0; n < 9; ++n) {
    float a = ss[n], c = dt[n];
#pragma unroll
    for (int off = 32; off > 0; off >>= 1) {
      a += __shfl_down(a, off, 64);
      c += __shfl_down(c, off, 64);
    }
    if (lane == 0) { red[0][n][wv] = a; red[1][n][wv] = c; }
  }
  __syncthreads();
  __shared__ float logit_s[9];
  if (t < 9) {
    float a = red[0][t][0] + red[0][t][1] + red[0][t][2] + red[0][t][3];
    float c = red[1][t][0] + red[1][t][1] + red[1][t][2] + red[1][t][3];
    logit_s[t] = c * rsqrtf(a * (1.0f / (float)DD) + 1e-8f);
  }
  __syncthreads();

  float lg[9], mx = -1e30f;
#pragma unroll
  for (int n = 0; n < 9; ++n) { lg[n] = logit_s[n]; mx = fmaxf(mx, lg[n]); }
  float den = 0.0f;
#pragma unroll
  for (int n = 0; n < 9; ++n) { lg[n] = __expf(lg[n] - mx); den += lg[n]; }
  const float inv = 1.0f / den;

  float h[8] = {0, 0, 0, 0, 0, 0, 0, 0};
#pragma unroll
  for (int n = 0; n < 9; ++n) {
    const float* rp = (n < 8) ? (blocks + (size_t)n * BTD + rowoff)
                              : (partial + rowoff);
    float4 v0 = *(const float4*)(rp + d0);
    float4 v1 = *(const float4*)(rp + 1024 + d0);
    const float a = lg[n] * inv;
    h[0] += a * v0.x; h[1] += a * v0.y; h[2] += a * v0.z; h[3] += a * v0.w;
    h[4] += a * v1.x; h[5] += a * v1.y; h[6] += a * v1.z; h[7] += a * v1.w;
  }

  float4 o0 = {h[0], h[1], h[2], h[3]}, o1 = {h[4], h[5], h[6], h[7]};
  *(float4*)(h_out + rowoff + d0) = o0;
  *(float4*)(h_out + rowoff + 1024 + d0) = o1;
  uint2 p0, p1;
  p0.x = (unsigned)f2bf(h[0]) | ((unsigned)f2bf(h[1]) << 16);
  p0.y = (unsigned)f2bf(h[2]) | ((unsigned)f2bf(h[3]) << 16);
  p1.x = (unsigned)f2bf(h[4]) | ((unsigned)f2bf(h[5]) << 16);
  p1.y = (unsigned)f2bf(h[6]) | ((unsigned)f2bf(h[7]) << 16);
  *(uint2*)(h_bf + rowoff + d0) = p0;
  *(uint2*)(h_bf + rowoff + 1024 + d0) = p1;
}

// ---------------------------------------------------------------------------
// 256-row 4-region bf16 GEMM with one-region-ahead register pipelining.
// BM=256, BK=64, 8 waves (2M x 4N), per-wave output 128 x (BN/4).
// LDS row byte-stride 128, XOR swizzle byte ^= ((row&7)<<4); staged via
// pre-swizzled global source (involution, rule #21).
// Per K-tile t (read buffer R=L_t, other O=L_{t+1}), 4 regions:
//   P1: read B[t] (R)        ; stage B  -> O (t+1) ; MFMA Q(mh0,nh0)
//   P2: read A_mh1[t] (R)    ; stage A13-> O (t+1) ; MFMA Q(mh0,nh1)
//   P3: read A_mh0[t+1] (O!) ; stage A02-> R (t+2) ; MFMA Q(mh1,nh1)
//   P4: (no reads)           ;                     ; MFMA Q(mh1,nh0)
// Every MFMA consumes fragments read >=1 region earlier -> compiler-counted
// lgkm waits are nearly free; LDS reads hide under previous MFMA cluster.
// Counted vmcnt: end-P1 / end-P2: vmcnt(6|4); end-P4: vmcnt(4). Never 0.
// EPI=0: C = gelu(A@B) -> bf16.  EPI=1: C = A@B + addend -> fp32.
template <int BN, int EPI>
__global__ __launch_bounds__(512, 2) void gemm256(
    const ushort_t* __restrict__ A, const ushort_t* __restrict__ BT,
    const int K, const int N, const int GX, ushort_t* __restrict__ Cb,
    const float* __restrict__ addend, float* __restrict__ Cf) {
  constexpr int BM = 256;
  constexpr int WCN = BN / 4;       // wave col span
  constexpr int MF = 8;             // m-frags per wave
  constexpr int NF = WCN / 16;      // n-frags per wave (4 or 2)
  constexpr int NH = NF / 2;        // n-frags per quadrant
  constexpr int NCB = BN / 64;      // B chunks (4 or 2)
  constexpr int AUS = BM * 64;      // A region size in ushorts (16384)
  constexpr int W12 = (BN == 256) ? 6 : 4;  // end-P1/end-P2 vmcnt

  __shared__ __align__(16) ushort_t lds0[(BM + BN) * 64];
  __shared__ __align__(16) ushort_t lds1[(BM + BN) * 64];

  const int t = threadIdx.x;
  const int lane = t & 63, wv = t >> 6;
  const int wr = wv >> 2, wc = wv & 3;
  const int fr = lane & 15;

  // T1: XCD-aware swizzle (grid % 8 == 0 in both instantiations)
  const int nwg = gridDim.x;
  const int wg = blockIdx.x;
  const int swz = (wg & 7) * (nwg >> 3) + (wg >> 3);
  const int bx = swz % GX, by = swz / GX;
  const int row0 = by * BM, col0 = bx * BN;

  // staging: thread t covers 16B at (row = chunk*64 + t/8, colbyte pre-swz)
  const int sr = t >> 3;
  const int scolb = ((t & 7) * 16) ^ ((sr & 7) << 4);  // inverse-swizzled src
  const ushort_t* gA = A + (size_t)(row0 + sr) * K + (scolb >> 1);
  const ushort_t* gB = BT + (size_t)(col0 + sr) * K + (scolb >> 1);

#define ST_A(W, c, KT)                                                         \
  ASYNC_COPY16(gA + (size_t)((c)*64) * K + (KT)*64, &W[(c)*4096 + wv * 512])
#define ST_B(W, c, KT)                                                         \
  ASYNC_COPY16(gB + (size_t)((c)*64) * K + (KT)*64,                            \
               &W[AUS + (c)*4096 + wv * 512])
#define STAGE_A02(W, KT) { ST_A(W, 0, KT); ST_A(W, 2, KT); }
#define STAGE_A13(W, KT) { ST_A(W, 1, KT); ST_A(W, 3, KT); }
#define STAGE_BB(W, KT)                                                        \
  { ST_B(W, 0, KT); ST_B(W, 1, KT);                                            \
    if (NCB == 4) { ST_B(W, 2, KT); ST_B(W, 3, KT); } }

  // frag read offsets: row*128 + ((ks*64 + (lane>>4)*16) ^ ((row&7)<<4));
  // row&7 == fr&7 for every frag row, so the XOR term is lane-constant.
  const int s_lane = (fr & 7) << 4;
  const int offk0 = ((lane >> 4) * 16) ^ s_lane;
  const int offk1 = (64 + (lane >> 4) * 16) ^ s_lane;
  const int aoffA = (wr * 128 + fr) * 128;  // + m*2048
  int boffB[NF];
#pragma unroll
  for (int n = 0; n < NF; ++n)
    boffB[n] = AUS * 2 + (wc * WCN + n * 16 + fr) * 128;

  // register fragment sets (single-assignment per K-tile; liveness per spec)
  bf16x8 af0[4][2], af1[4][2], bfr[NF][2];

#define READ_AF0(Lb)                                                           \
  _Pragma("unroll") for (int m = 0; m < 4; ++m) {                              \
    af0[m][0] = *(const bf16x8*)((const char*)(Lb) + aoffA + m * 2048 + offk0);\
    af0[m][1] = *(const bf16x8*)((const char*)(Lb) + aoffA + m * 2048 + offk1);\
  }
#define READ_AF1(Lb)                                                           \
  _Pragma("unroll") for (int m = 0; m < 4; ++m) {                              \
    af1[m][0] =                                                                \
        *(const bf16x8*)((const char*)(Lb) + aoffA + (4 + m) * 2048 + offk0);  \
    af1[m][1] =                                                                \
        *(const bf16x8*)((const char*)(Lb) + aoffA + (4 + m) * 2048 + offk1);  \
  }
#define READ_B(Lb)                                                             \
  _Pragma("unroll") for (int n = 0; n < NF; ++n) {                             \
    bfr[n][0] = *(const bf16x8*)((const char*)(Lb) + boffB[n] + offk0);        \
    bfr[n][1] = *(const bf16x8*)((const char*)(Lb) + boffB[n] + offk1);        \
  }

  f32x4 acc[MF][NF];
#pragma unroll
  for (int m = 0; m < 4; ++m)
#pragma unroll
    for (int n = 0; n < NF; ++n) {
      f32x4 z = {0.f, 0.f, 0.f, 0.f};
      acc[m][n] = z; acc[4 + m][n] = z;
    }

#define MFMA_(a, b, c) __builtin_amdgcn_mfma_f32_16x16x32_bf16(a, b, c, 0, 0, 0)
  // k-outer: dep distance 4*NH between same-acc MFMAs
#define QUAD(AF, MO, NO)                                                       \
  _Pragma("unroll") for (int ks = 0; ks < 2; ++ks)                             \
    _Pragma("unroll") for (int m = 0; m < 4; ++m)                              \
      _Pragma("unroll") for (int n = 0; n < NH; ++n)                           \
        acc[MO + m][NO + n] =                                                  \
            MFMA_(AF[m][ks], bfr[NO + n][ks], acc[MO + m][NO + n]);

#define HALF(Rb, Ob, T)                                                        \
  {                                                                            \
    const bool s1 = (T) + 1 < NT, s2 = (T) + 2 < NT;                           \
    /* P1: read B[t]; stage B->O(t+1); MFMA (mh0,nh0) */                       \
    READ_B(Rb);                                                                \
    if (s1) STAGE_BB(Ob, (T) + 1);                                             \
    __builtin_amdgcn_s_barrier();                                              \
    __builtin_amdgcn_s_setprio(1);                                             \
    QUAD(af0, 0, 0);                                                           \
    __builtin_amdgcn_s_setprio(0);                                             \
    wait_vmcnt<W12>();                                                         \
    __builtin_amdgcn_s_barrier();                                              \
    /* P2: read A_mh1[t]; stage A13->O(t+1); MFMA (mh0,nh1) */                 \
    READ_AF1(Rb);                                                              \
    if (s1) STAGE_A13(Ob, (T) + 1);                                            \
    __builtin_amdgcn_s_barrier();                                              \
    __builtin_amdgcn_s_setprio(1);                                             \
    QUAD(af0, 0, NH);                                                          \
    __builtin_amdgcn_s_setprio(0);                                             \
    wait_vmcnt<W12>();                                                         \
    __builtin_amdgcn_s_barrier();                                              \
    /* P3: read A_mh0[t+1] from O; stage A02->R(t+2); MFMA (mh1,nh1) */        \
    READ_AF0(Ob);                                                              \
    if (s2) STAGE_A02(Rb, (T) + 2);                                            \
    __builtin_amdgcn_s_barrier();                                              \
    __builtin_amdgcn_s_setprio(1);                                             \
    QUAD(af1, 4, NH);                                                          \
    __builtin_amdgcn_s_setprio(0);                                             \
    __builtin_amdgcn_s_barrier();                                              \
    /* P4: no reads; MFMA (mh1,nh0) */                                         \
    __builtin_amdgcn_s_barrier();                                              \
    __builtin_amdgcn_s_setprio(1);                                             \
    QUAD(af1, 4, 0);                                                           \
    __builtin_amdgcn_s_setprio(0);                                             \
    wait_vmcnt<4>();                                                           \
    __builtin_amdgcn_s_barrier();                                              \
  }

  const int NT = K >> 6;  // K-tiles (even: 32 or 128)

  // prologue: L0 fully (A02, B, A13) + L1's A02 (issued oldest->newest)
  STAGE_A02(lds0, 0);
  STAGE_BB(lds0, 0);
  STAGE_A13(lds0, 0);
  STAGE_A02(lds1, 1);
  wait_vmcnt<2>();  // L0 landed; L1's A02 in flight
  __builtin_amdgcn_s_barrier();
  READ_AF0(lds0);   // af0[0]

  for (int kt = 0; kt < NT; kt += 2) {
    HALF(lds0, lds1, kt);
    HALF(lds1, lds0, kt + 1);
  }

  const int r4 = (lane >> 4) * 4;
#pragma unroll
  for (int m = 0; m < MF; ++m) {
    const int grow = row0 + wr * 128 + m * 16 + r4;
#pragma unroll
    for (int n = 0; n < NF; ++n) {
      const int gcol = col0 + wc * WCN + n * 16 + fr;
#pragma unroll
      for (int r = 0; r < 4; ++r) {
        const float v = acc[m][n][r];
        const size_t idx = (size_t)(grow + r) * N + gcol;
        if (EPI == 0) {
          Cb[idx] = f2bf(gelu_tanh(v));
        } else {
          Cf[idx] = v + addend[idx];
        }
      }
    }
  }
#undef HALF
#undef QUAD
#undef MFMA_
#undef READ_AF0
#undef READ_AF1
#undef READ_B
#undef STAGE_A02
#undef STAGE_A13
#undef STAGE_BB
#undef ST_A
#undef ST_B
}

// ---------------------------------------------------------------------------
extern "C" void kernel_launch(void* const* d_in, const int* in_sizes, int n_in,
                              void* d_out, int out_size, void* d_ws,
                              size_t ws_size, hipStream_t stream) {
  const float* blocks = (const float*)d_in[0];
  const float* partial = (const float*)d_in[1];
  const float* proj_w = (const float*)d_in[2];
  const float* norm_scale = (const float*)d_in[3];
  const float* w1 = (const float*)d_in[4];
  const float* w2 = (const float*)d_in[5];

  float* out = (float*)d_out;
  float* h_out = out;                 // [B,T,D] fp32
  float* new_partial = out + BTD;     // [B,T,D] fp32

  char* ws = (char*)d_ws;
  ushort_t* h_bf = (ushort_t*)ws;                                        // 16 MB
  ushort_t* w1T = (ushort_t*)(ws + (size_t)16777216);                    // 32 MB (F x D)
  ushort_t* w2T = (ushort_t*)(ws + (size_t)16777216 + 33554432);         // 32 MB (D x F)
  ushort_t* act = (ushort_t*)(ws + (size_t)16777216 + 2 * 33554432ull);  // 64 MB (M x F)

  // weight convert + transpose to (N x K) bf16
  transpose_conv<<<dim3(FF / 32, DD / 32), 256, 0, stream>>>(w1, w1T, DD, FF);
  transpose_conv<<<dim3(DD / 32, FF / 32), 256, 0, stream>>>(w2, w2T, FF, DD);

  // fused attention -> h (fp32 out) + h (bf16 for GEMM)
  attn_fuse<<<MM, 256, 0, stream>>>(blocks, partial, proj_w, norm_scale, h_out,
                                    h_bf);

  // FFN: act = gelu(h @ W1) ; new_partial = act @ W2 + partial
  gemm256<256, 0><<<(FF / 256) * (MM / 256), 512, 0, stream>>>(
      h_bf, w1T, DD, FF, FF / 256, act, nullptr, nullptr);
  gemm256<128, 1><<<(DD / 128) * (MM / 256), 512, 0, stream>>>(
      act, w2T, FF, DD, DD / 128, nullptr, partial, new_partial);
}

// Round 5
// 433.661 us; speedup vs baseline: 1.2514x; 1.2514x over previous
//
#include <hip/hip_runtime.h>

typedef unsigned short ushort_t;
typedef __bf16 bf16x8 __attribute__((ext_vector_type(8)));
typedef float f32x4 __attribute__((ext_vector_type(4)));

// sizes (fixed by the problem)
#define NB 8
#define BB 2
#define TT 2048
#define DD 2048
#define FF 8192
#define MM (BB * TT)          // 4096 rows
#define BTD ((size_t)BB * TT * DD)   // 8388608

__device__ __forceinline__ unsigned short f2bf(float f) {
  unsigned int u = __float_as_uint(f);
  u += 0x7FFFu + ((u >> 16) & 1u);
  return (unsigned short)(u >> 16);
}

__device__ __forceinline__ float gelu_tanh(float x) {
  float u = 0.7978845608028654f * (x + 0.044715f * x * x * x);
  float e = __expf(2.0f * u);
  float th = 1.0f - 2.0f / (e + 1.0f);   // robust tanh(u), e=inf -> 1
  return 0.5f * x * (1.0f + th);
}

template <int N>
__device__ __forceinline__ void wait_vmcnt() {
  if constexpr (N == 0) asm volatile("s_waitcnt vmcnt(0)" ::: "memory");
  else if constexpr (N == 8) asm volatile("s_waitcnt vmcnt(8)" ::: "memory");
  else if constexpr (N == 10) asm volatile("s_waitcnt vmcnt(10)" ::: "memory");
}

#define ASYNC_COPY16(gp, lp)                                                   \
  __builtin_amdgcn_global_load_lds(                                            \
      (__attribute__((address_space(1))) void*)(gp),                           \
      (__attribute__((address_space(3))) void*)(lp), 16, 0, 0)

// ---------------------------------------------------------------------------
// fp32 (R x C) -> bf16 transposed (C x R)
__global__ __launch_bounds__(256) void transpose_conv(
    const float* __restrict__ in, ushort_t* __restrict__ out, int R, int C) {
  __shared__ float tile[32][33];
  const int tx = threadIdx.x & 31, ty = threadIdx.x >> 5;
  const int r0 = blockIdx.y * 32, c0 = blockIdx.x * 32;
#pragma unroll
  for (int i = 0; i < 32; i += 8)
    tile[ty + i][tx] = in[(size_t)(r0 + ty + i) * C + (c0 + tx)];
  __syncthreads();
#pragma unroll
  for (int i = 0; i < 32; i += 8)
    out[(size_t)(c0 + ty + i) * R + (r0 + tx)] = f2bf(tile[tx][ty + i]);
}

// ---------------------------------------------------------------------------
// Fused block-attention: ONE PASS over V. Each thread holds its 8 elements of
// all 9 rows in registers (72 VGPR), halving HBM traffic vs two-pass.
__global__ __launch_bounds__(256) void attn_fuse(
    const float* __restrict__ blocks, const float* __restrict__ partial,
    const float* __restrict__ proj_w, const float* __restrict__ norm_scale,
    float* __restrict__ h_out, ushort_t* __restrict__ h_bf) {
  const int t = threadIdx.x;
  const int bt = blockIdx.x;
  const size_t rowoff = (size_t)bt * DD;
  const int d0 = t * 4;

  float w[8];
  {
    float4 ns = *(const float4*)(norm_scale + d0);
    float4 pw = *(const float4*)(proj_w + d0);
    w[0] = ns.x * pw.x; w[1] = ns.y * pw.y; w[2] = ns.z * pw.z; w[3] = ns.w * pw.w;
    ns = *(const float4*)(norm_scale + 1024 + d0);
    pw = *(const float4*)(proj_w + 1024 + d0);
    w[4] = ns.x * pw.x; w[5] = ns.y * pw.y; w[6] = ns.z * pw.z; w[7] = ns.w * pw.w;
  }

  float vv[9][8];
  float ss[9], dt[9];
#pragma unroll
  for (int n = 0; n < 9; ++n) {
    const float* rp = (n < 8) ? (blocks + (size_t)n * BTD + rowoff)
                              : (partial + rowoff);
    float4 v0 = *(const float4*)(rp + d0);
    float4 v1 = *(const float4*)(rp + 1024 + d0);
    vv[n][0] = v0.x; vv[n][1] = v0.y; vv[n][2] = v0.z; vv[n][3] = v0.w;
    vv[n][4] = v1.x; vv[n][5] = v1.y; vv[n][6] = v1.z; vv[n][7] = v1.w;
    float a = 0.f, c = 0.f;
#pragma unroll
    for (int j = 0; j < 8; ++j) {
      a += vv[n][j] * vv[n][j];
      c += vv[n][j] * w[j];
    }
    ss[n] = a; dt[n] = c;
  }

  __shared__ float red[2][9][4];
  const int lane = t & 63, wv = t >> 6;
#pragma unroll
  for (int n = 0; n < 9; ++n) {
    float a = ss[n], c = dt[n];
#pragma unroll
    for (int off = 32; off > 0; off >>= 1) {
      a += __shfl_down(a, off, 64);
      c += __shfl_down(c, off, 64);
    }
    if (lane == 0) { red[0][n][wv] = a; red[1][n][wv] = c; }
  }
  __syncthreads();
  __shared__ float logit_s[9];
  if (t < 9) {
    float a = red[0][t][0] + red[0][t][1] + red[0][t][2] + red[0][t][3];
    float c = red[1][t][0] + red[1][t][1] + red[1][t][2] + red[1][t][3];
    logit_s[t] = c * rsqrtf(a * (1.0f / (float)DD) + 1e-8f);
  }
  __syncthreads();

  float lg[9], mx = -1e30f;
#pragma unroll
  for (int n = 0; n < 9; ++n) { lg[n] = logit_s[n]; mx = fmaxf(mx, lg[n]); }
  float den = 0.0f;
#pragma unroll
  for (int n = 0; n < 9; ++n) { lg[n] = __expf(lg[n] - mx); den += lg[n]; }
  const float inv = 1.0f / den;

  float h[8] = {0, 0, 0, 0, 0, 0, 0, 0};
#pragma unroll
  for (int n = 0; n < 9; ++n) {
    const float a = lg[n] * inv;
#pragma unroll
    for (int j = 0; j < 8; ++j) h[j] += a * vv[n][j];
  }

  float4 o0 = {h[0], h[1], h[2], h[3]}, o1 = {h[4], h[5], h[6], h[7]};
  *(float4*)(h_out + rowoff + d0) = o0;
  *(float4*)(h_out + rowoff + 1024 + d0) = o1;
  uint2 p0, p1;
  p0.x = (unsigned)f2bf(h[0]) | ((unsigned)f2bf(h[1]) << 16);
  p0.y = (unsigned)f2bf(h[2]) | ((unsigned)f2bf(h[3]) << 16);
  p1.x = (unsigned)f2bf(h[4]) | ((unsigned)f2bf(h[5]) << 16);
  p1.y = (unsigned)f2bf(h[6]) | ((unsigned)f2bf(h[7]) << 16);
  *(uint2*)(h_bf + rowoff + d0) = p0;
  *(uint2*)(h_bf + rowoff + 1024 + d0) = p1;
}

// ---------------------------------------------------------------------------
// 256-row 4-phase bf16 GEMM, m201-fidelity port.
// BM=256, BK=64, 8 waves (2M x 4N), per-wave output 128 x (BN/4).
// LDS row byte-stride 128, XOR swizzle byte ^= ((row&7)<<4); staged via
// pre-swizzled global source (involution).  Double-buffered K-tiles.
// Per K-tile t (buffer Rb): phases {reads; stages; sched_barrier; barrier;
// setprio1; MFMA quadrant; setprio0; [vmcnt]; barrier}:
//   P1: read B-nh0 (4|2) + A-m03 (8)           ; MFMA (m03,nh0)
//   P2: read B-nh1 (4|2); stage A{0,2}[t+2]->Rb; MFMA (m03,nh1); vmcnt(WP)
//   P3: read A-m47 (8)  ; stage B-all[t+2]->Rb ; MFMA (m47,nh1)
//   P4:                 ; stage A{1,3}[t+2]->Rb; MFMA (m47,nh0); vmcnt(WP)
// B fragments held in regs across the whole tile (b0 reused in P4).
// Regions staged exactly one phase after their last read (barrier-separated
// => race-free).  Prefetch slack = 6 phases; counted waits verified:
//   batches/tile: P2:+2, P3:+NCB, P4:+2 ; prologue 2 full tiles.
//   end-P4(t-1) must cover Ph1(t) reads; end-P2(t) covers Ph3(t). Both
//   N = 10 (BN=256) / 8 (BN=128), uniform incl. boundary tiles.
// EPI=0: C = gelu(A@B) -> bf16.  EPI=1: C = A@B + addend -> fp32.
template <int BN, int EPI>
__global__ __launch_bounds__(512, 2) void gemm256(
    const ushort_t* __restrict__ A, const ushort_t* __restrict__ BT,
    const int K, const int N, const int GX, ushort_t* __restrict__ Cb,
    const float* __restrict__ addend, float* __restrict__ Cf) {
  constexpr int BM = 256;
  constexpr int WCN = BN / 4;       // wave col span (64 | 32)
  constexpr int MF = 8;             // m-frags per wave
  constexpr int NF = WCN / 16;      // n-frags per wave (4 | 2)
  constexpr int NH = NF / 2;        // n-frags per quadrant (2 | 1)
  constexpr int NCB = BN / 64;      // B chunks (4 | 2)
  constexpr int AUS = BM * 64;      // A region in ushorts (16384)
  constexpr int WP = (BN == 256) ? 10 : 8;

  __shared__ __align__(16) ushort_t lds0[(BM + BN) * 64];
  __shared__ __align__(16) ushort_t lds1[(BM + BN) * 64];

  const int t = threadIdx.x;
  const int lane = t & 63, wv = t >> 6;
  const int wr = wv >> 2, wc = wv & 3;
  const int fr = lane & 15;

  // T1: XCD-aware swizzle (grid % 8 == 0 in both instantiations)
  const int nwg = gridDim.x;
  const int wg = blockIdx.x;
  const int swz = (wg & 7) * (nwg >> 3) + (wg >> 3);
  const int bx = swz % GX, by = swz / GX;
  const int row0 = by * BM, col0 = bx * BN;

  // staging: thread t covers 16B at (row = chunk*64 + t/8, colbyte pre-swz)
  const int sr = t >> 3;
  const int scolb = ((t & 7) * 16) ^ ((sr & 7) << 4);  // inverse-swizzled src
  const ushort_t* gA = A + (size_t)(row0 + sr) * K + (scolb >> 1);
  const ushort_t* gB = BT + (size_t)(col0 + sr) * K + (scolb >> 1);

#define ST_A(W, c, KT)                                                         \
  ASYNC_COPY16(gA + (size_t)((c)*64) * K + (KT)*64, &W[(c)*4096 + wv * 512])
#define ST_B(W, c, KT)                                                         \
  ASYNC_COPY16(gB + (size_t)((c)*64) * K + (KT)*64,                            \
               &W[AUS + (c)*4096 + wv * 512])
#define STAGE_BALL(W, KT)                                                      \
  { _Pragma("unroll") for (int _c = 0; _c < NCB; ++_c) ST_B(W, _c, KT); }

  // frag read offsets: row*128 + ((ks*64 + (lane>>4)*16) ^ ((row&7)<<4));
  // row&7 == fr&7 for every frag row, so the XOR term is lane-constant.
  const int s_lane = (fr & 7) << 4;
  const int offk0 = ((lane >> 4) * 16) ^ s_lane;
  const int offk1 = (64 + (lane >> 4) * 16) ^ s_lane;
  const int aoffA = (wr * 128 + fr) * 128;  // + m*2048
  int boffB[NF];
#pragma unroll
  for (int n = 0; n < NF; ++n)
    boffB[n] = AUS * 2 + (wc * WCN + n * 16 + fr) * 128;

  // fragment registers: A half (8 b128) + B full tile (b0,b1: 8|4 b128)
  bf16x8 af[4][2], b0[NH][2], b1[NH][2];

#define READ_A(Lb, MO)                                                         \
  _Pragma("unroll") for (int m = 0; m < 4; ++m) {                              \
    af[m][0] =                                                                 \
        *(const bf16x8*)((const char*)(Lb) + aoffA + (MO + m) * 2048 + offk0); \
    af[m][1] =                                                                 \
        *(const bf16x8*)((const char*)(Lb) + aoffA + (MO + m) * 2048 + offk1); \
  }
#define READ_B(Lb, DST, NO)                                                    \
  _Pragma("unroll") for (int n = 0; n < NH; ++n) {                             \
    DST[n][0] = *(const bf16x8*)((const char*)(Lb) + boffB[NO + n] + offk0);   \
    DST[n][1] = *(const bf16x8*)((const char*)(Lb) + boffB[NO + n] + offk1);   \
  }

  f32x4 acc[MF][NF];
#pragma unroll
  for (int m = 0; m < MF; ++m)
#pragma unroll
    for (int n = 0; n < NF; ++n) {
      f32x4 z = {0.f, 0.f, 0.f, 0.f};
      acc[m][n] = z;
    }

#define MFMA_(a, b, c) __builtin_amdgcn_mfma_f32_16x16x32_bf16(a, b, c, 0, 0, 0)
  // ks-outer: dep distance 4*NH between same-acc MFMAs
#define QUAD(BF, MO, NO)                                                       \
  _Pragma("unroll") for (int ks = 0; ks < 2; ++ks)                             \
    _Pragma("unroll") for (int m = 0; m < 4; ++m)                              \
      _Pragma("unroll") for (int n = 0; n < NH; ++n)                           \
        acc[MO + m][NO + n] =                                                  \
            MFMA_(af[m][ks], BF[n][ks], acc[MO + m][NO + n]);

#define HALF(Rb, KT)                                                           \
  {                                                                            \
    const bool _s = (KT) + 2 < NT;                                             \
    /* P1: read B-nh0 + A-m03 */                                               \
    READ_B(Rb, b0, 0);                                                         \
    READ_A(Rb, 0);                                                             \
    __builtin_amdgcn_sched_barrier(0);                                         \
    __builtin_amdgcn_s_barrier();                                              \
    __builtin_amdgcn_s_setprio(1);                                             \
    QUAD(b0, 0, 0);                                                            \
    __builtin_amdgcn_s_setprio(0);                                             \
    __builtin_amdgcn_s_barrier();                                              \
    /* P2: read B-nh1; stage A{0,2}[t+2] */                                    \
    READ_B(Rb, b1, NH);                                                        \
    if (_s) { ST_A(Rb, 0, (KT) + 2); ST_A(Rb, 2, (KT) + 2); }                  \
    __builtin_amdgcn_sched_barrier(0);                                         \
    __builtin_amdgcn_s_barrier();                                              \
    __builtin_amdgcn_s_setprio(1);                                             \
    QUAD(b1, 0, NH);                                                           \
    __builtin_amdgcn_s_setprio(0);                                             \
    wait_vmcnt<WP>();                                                          \
    __builtin_amdgcn_s_barrier();                                              \
    /* P3: read A-m47; stage B-all[t+2] */                                     \
    READ_A(Rb, 4);                                                             \
    if (_s) STAGE_BALL(Rb, (KT) + 2);                                          \
    __builtin_amdgcn_sched_barrier(0);                                         \
    __builtin_amdgcn_s_barrier();                                              \
    __builtin_amdgcn_s_setprio(1);                                             \
    QUAD(b1, 4, NH);                                                           \
    __builtin_amdgcn_s_setprio(0);                                             \
    __builtin_amdgcn_s_barrier();                                              \
    /* P4: stage A{1,3}[t+2]; consume held b0 */                               \
    if (_s) { ST_A(Rb, 1, (KT) + 2); ST_A(Rb, 3, (KT) + 2); }                  \
    __builtin_amdgcn_sched_barrier(0);                                         \
    __builtin_amdgcn_s_barrier();                                              \
    __builtin_amdgcn_s_setprio(1);                                             \
    QUAD(b0, 4, 0);                                                            \
    __builtin_amdgcn_s_setprio(0);                                             \
    wait_vmcnt<WP>();                                                          \
    __builtin_amdgcn_s_barrier();                                              \
  }

  const int NT = K >> 6;  // K-tiles (even; >= 4)

  // prologue: t0 -> lds0, t1 -> lds1, batch order A02, B, A13 per tile
  ST_A(lds0, 0, 0); ST_A(lds0, 2, 0);
  STAGE_BALL(lds0, 0);
  ST_A(lds0, 1, 0); ST_A(lds0, 3, 0);
  ST_A(lds1, 0, 1); ST_A(lds1, 2, 1);
  STAGE_BALL(lds1, 1);
  ST_A(lds1, 1, 1); ST_A(lds1, 3, 1);
  wait_vmcnt<WP>();  // t0's A02 + B landed
  __builtin_amdgcn_s_barrier();

  for (int kt = 0; kt < NT; kt += 2) {
    HALF(lds0, kt);
    HALF(lds1, kt + 1);
  }

  const int r4 = (lane >> 4) * 4;
#pragma unroll
  for (int m = 0; m < MF; ++m) {
    const int grow = row0 + wr * 128 + m * 16 + r4;
#pragma unroll
    for (int n = 0; n < NF; ++n) {
      const int gcol = col0 + wc * WCN + n * 16 + fr;
#pragma unroll
      for (int r = 0; r < 4; ++r) {
        const float v = acc[m][n][r];
        const size_t idx = (size_t)(grow + r) * N + gcol;
        if (EPI == 0) {
          Cb[idx] = f2bf(gelu_tanh(v));
        } else {
          Cf[idx] = v + addend[idx];
        }
      }
    }
  }
#undef HALF
#undef QUAD
#undef MFMA_
#undef READ_A
#undef READ_B
#undef STAGE_BALL
#undef ST_A
#undef ST_B
}

// ---------------------------------------------------------------------------
extern "C" void kernel_launch(void* const* d_in, const int* in_sizes, int n_in,
                              void* d_out, int out_size, void* d_ws,
                              size_t ws_size, hipStream_t stream) {
  const float* blocks = (const float*)d_in[0];
  const float* partial = (const float*)d_in[1];
  const float* proj_w = (const float*)d_in[2];
  const float* norm_scale = (const float*)d_in[3];
  const float* w1 = (const float*)d_in[4];
  const float* w2 = (const float*)d_in[5];

  float* out = (float*)d_out;
  float* h_out = out;                 // [B,T,D] fp32
  float* new_partial = out + BTD;     // [B,T,D] fp32

  char* ws = (char*)d_ws;
  ushort_t* h_bf = (ushort_t*)ws;                                        // 16 MB
  ushort_t* w1T = (ushort_t*)(ws + (size_t)16777216);                    // 32 MB (F x D)
  ushort_t* w2T = (ushort_t*)(ws + (size_t)16777216 + 33554432);         // 32 MB (D x F)
  ushort_t* act = (ushort_t*)(ws + (size_t)16777216 + 2 * 33554432ull);  // 64 MB (M x F)

  // weight convert + transpose to (N x K) bf16
  transpose_conv<<<dim3(FF / 32, DD / 32), 256, 0, stream>>>(w1, w1T, DD, FF);
  transpose_conv<<<dim3(DD / 32, FF / 32), 256, 0, stream>>>(w2, w2T, FF, DD);

  // fused attention -> h (fp32 out) + h (bf16 for GEMM)
  attn_fuse<<<MM, 256, 0, stream>>>(blocks, partial, proj_w, norm_scale, h_out,
                                    h_bf);

  // FFN: act = gelu(h @ W1) ; new_partial = act @ W2 + partial
  gemm256<256, 0><<<(FF / 256) * (MM / 256), 512, 0, stream>>>(
      h_bf, w1T, DD, FF, FF / 256, act, nullptr, nullptr);
  gemm256<128, 1><<<(DD / 128) * (MM / 256), 512, 0, stream>>>(
      act, w2T, FF, DD, DD / 128, nullptr, partial, new_partial);
}

// Round 6
// 393.777 us; speedup vs baseline: 1.3782x; 1.1013x over previous
//
#include <hip/hip_runtime.h>

typedef unsigned short ushort_t;
typedef __bf16 bf16x8 __attribute__((ext_vector_type(8)));
typedef float f32x4 __attribute__((ext_vector_type(4)));

// sizes (fixed by the problem)
#define NB 8
#define BB 2
#define TT 2048
#define DD 2048
#define FF 8192
#define MM (BB * TT)          // 4096 rows
#define BTD ((size_t)BB * TT * DD)   // 8388608

__device__ __forceinline__ unsigned short f2bf(float f) {
  unsigned int u = __float_as_uint(f);
  u += 0x7FFFu + ((u >> 16) & 1u);
  return (unsigned short)(u >> 16);
}

__device__ __forceinline__ float gelu_tanh(float x) {
  float u = 0.7978845608028654f * (x + 0.044715f * x * x * x);
  float e = __expf(2.0f * u);
  float th = 1.0f - 2.0f / (e + 1.0f);   // robust tanh(u), e=inf -> 1
  return 0.5f * x * (1.0f + th);
}

template <int N>
__device__ __forceinline__ void wait_vmcnt() {
  if constexpr (N == 0) asm volatile("s_waitcnt vmcnt(0)" ::: "memory");
  else if constexpr (N == 8) asm volatile("s_waitcnt vmcnt(8)" ::: "memory");
}

#define ASYNC_COPY16(gp, lp)                                                   \
  __builtin_amdgcn_global_load_lds(                                            \
      (__attribute__((address_space(1))) void*)(gp),                           \
      (__attribute__((address_space(3))) void*)(lp), 16, 0, 0)

// ---------------------------------------------------------------------------
// fp32 (R x C) -> bf16 transposed (C x R)
__global__ __launch_bounds__(256) void transpose_conv(
    const float* __restrict__ in, ushort_t* __restrict__ out, int R, int C) {
  __shared__ float tile[32][33];
  const int tx = threadIdx.x & 31, ty = threadIdx.x >> 5;
  const int r0 = blockIdx.y * 32, c0 = blockIdx.x * 32;
#pragma unroll
  for (int i = 0; i < 32; i += 8)
    tile[ty + i][tx] = in[(size_t)(r0 + ty + i) * C + (c0 + tx)];
  __syncthreads();
#pragma unroll
  for (int i = 0; i < 32; i += 8)
    out[(size_t)(c0 + ty + i) * R + (r0 + tx)] = f2bf(tile[tx][ty + i]);
}

// ---------------------------------------------------------------------------
// Fused block-attention: ONE PASS over V (V rows held in registers).
__global__ __launch_bounds__(256) void attn_fuse(
    const float* __restrict__ blocks, const float* __restrict__ partial,
    const float* __restrict__ proj_w, const float* __restrict__ norm_scale,
    float* __restrict__ h_out, ushort_t* __restrict__ h_bf) {
  const int t = threadIdx.x;
  const int bt = blockIdx.x;
  const size_t rowoff = (size_t)bt * DD;
  const int d0 = t * 4;

  float w[8];
  {
    float4 ns = *(const float4*)(norm_scale + d0);
    float4 pw = *(const float4*)(proj_w + d0);
    w[0] = ns.x * pw.x; w[1] = ns.y * pw.y; w[2] = ns.z * pw.z; w[3] = ns.w * pw.w;
    ns = *(const float4*)(norm_scale + 1024 + d0);
    pw = *(const float4*)(proj_w + 1024 + d0);
    w[4] = ns.x * pw.x; w[5] = ns.y * pw.y; w[6] = ns.z * pw.z; w[7] = ns.w * pw.w;
  }

  float vv[9][8];
  float ss[9], dt[9];
#pragma unroll
  for (int n = 0; n < 9; ++n) {
    const float* rp = (n < 8) ? (blocks + (size_t)n * BTD + rowoff)
                              : (partial + rowoff);
    float4 v0 = *(const float4*)(rp + d0);
    float4 v1 = *(const float4*)(rp + 1024 + d0);
    vv[n][0] = v0.x; vv[n][1] = v0.y; vv[n][2] = v0.z; vv[n][3] = v0.w;
    vv[n][4] = v1.x; vv[n][5] = v1.y; vv[n][6] = v1.z; vv[n][7] = v1.w;
    float a = 0.f, c = 0.f;
#pragma unroll
    for (int j = 0; j < 8; ++j) {
      a += vv[n][j] * vv[n][j];
      c += vv[n][j] * w[j];
    }
    ss[n] = a; dt[n] = c;
  }

  __shared__ float red[2][9][4];
  const int lane = t & 63, wv = t >> 6;
#pragma unroll
  for (int n = 0; n < 9; ++n) {
    float a = ss[n], c = dt[n];
#pragma unroll
    for (int off = 32; off > 0; off >>= 1) {
      a += __shfl_down(a, off, 64);
      c += __shfl_down(c, off, 64);
    }
    if (lane == 0) { red[0][n][wv] = a; red[1][n][wv] = c; }
  }
  __syncthreads();
  __shared__ float logit_s[9];
  if (t < 9) {
    float a = red[0][t][0] + red[0][t][1] + red[0][t][2] + red[0][t][3];
    float c = red[1][t][0] + red[1][t][1] + red[1][t][2] + red[1][t][3];
    logit_s[t] = c * rsqrtf(a * (1.0f / (float)DD) + 1e-8f);
  }
  __syncthreads();

  float lg[9], mx = -1e30f;
#pragma unroll
  for (int n = 0; n < 9; ++n) { lg[n] = logit_s[n]; mx = fmaxf(mx, lg[n]); }
  float den = 0.0f;
#pragma unroll
  for (int n = 0; n < 9; ++n) { lg[n] = __expf(lg[n] - mx); den += lg[n]; }
  const float inv = 1.0f / den;

  float h[8] = {0, 0, 0, 0, 0, 0, 0, 0};
#pragma unroll
  for (int n = 0; n < 9; ++n) {
    const float a = lg[n] * inv;
#pragma unroll
    for (int j = 0; j < 8; ++j) h[j] += a * vv[n][j];
  }

  float4 o0 = {h[0], h[1], h[2], h[3]}, o1 = {h[4], h[5], h[6], h[7]};
  *(float4*)(h_out + rowoff + d0) = o0;
  *(float4*)(h_out + rowoff + 1024 + d0) = o1;
  uint2 p0, p1;
  p0.x = (unsigned)f2bf(h[0]) | ((unsigned)f2bf(h[1]) << 16);
  p0.y = (unsigned)f2bf(h[2]) | ((unsigned)f2bf(h[3]) << 16);
  p1.x = (unsigned)f2bf(h[4]) | ((unsigned)f2bf(h[5]) << 16);
  p1.y = (unsigned)f2bf(h[6]) | ((unsigned)f2bf(h[7]) << 16);
  *(uint2*)(h_bf + rowoff + d0) = p0;
  *(uint2*)(h_bf + rowoff + 1024 + d0) = p1;
}

// ---------------------------------------------------------------------------
// 128x128 bf16 GEMM, BK=64, 4 waves (2x2), per-wave 64x64 (4x4 16x16x32).
// LDS 64 KB (2 buf x (A+B) 32 KB) -> 2 INDEPENDENT blocks per CU: block A's
// LDS read-drain overlaps block B's MFMA cluster (m114/m97 mechanism),
// instead of the single-barrier-domain lockstep that pinned MfmaUtil at 33%.
// XOR swizzle byte ^= ((row&7)<<4) via pre-swizzled global source (0 bank
// conflicts, verified R2-R5).  Counted vmcnt(8) (never 0 mid-loop); stage for
// tile t+2 issued right after the readers-done barrier of tile t (2-tile
// slack covers HBM latency).  2D XCD supertile: XCD x owns an SBY x SBX block
// square -> A+B L2/L3 footprint ~16 MB/XCD (vs B fully re-fetched per XCD).
// EPI=0: C = gelu(A@B) -> bf16.  EPI=1: C = A@B + addend -> fp32.
template <int SBY, int SBX, int MCX, int EPI>
__global__ __launch_bounds__(256, 2) void gemm128(
    const ushort_t* __restrict__ A, const ushort_t* __restrict__ BT,
    const int K, const int N, ushort_t* __restrict__ Cb,
    const float* __restrict__ addend, float* __restrict__ Cf) {
  constexpr int AUS = 128 * 64;  // one matrix tile in ushorts (16 KB)

  __shared__ __align__(16) ushort_t lds0[2 * AUS];
  __shared__ __align__(16) ushort_t lds1[2 * AUS];

  const int t = threadIdx.x;
  const int lane = t & 63, wv = t >> 6;
  const int wr = (wv >> 1) * 64, wc = (wv & 1) * 64;
  const int fr = lane & 15;

  // 2D XCD supertile: XCD = wg&7 owns a contiguous SBYxSBX square of blocks.
  const int wg = blockIdx.x;
  const int xcd = wg & 7, local = wg >> 3;
  const int sby = local / SBX, sbx = local % SBX;
  const int by = (xcd / MCX) * SBY + sby;
  const int bx = (xcd % MCX) * SBX + sbx;
  const int row0 = by * 128, col0 = bx * 128;

  // staging: batch j covers rows j*32 + (t>>3), 16B col-slot (t&7), col
  // pre-swizzled so linear LDS writes produce the XOR layout.
  const int sr = t >> 3;                               // 0..31
  const int scolb = ((t & 7) * 16) ^ ((sr & 7) << 4);  // inverse-swizzled src
  const ushort_t* gA = A + (size_t)(row0 + sr) * K + (scolb >> 1);
  const ushort_t* gB = BT + (size_t)(col0 + sr) * K + (scolb >> 1);

#define ST_A(W, j, KT)                                                         \
  ASYNC_COPY16(gA + (size_t)((j)*32) * K + (KT)*64, &W[(j)*2048 + wv * 512])
#define ST_B(W, j, KT)                                                         \
  ASYNC_COPY16(gB + (size_t)((j)*32) * K + (KT)*64,                            \
               &W[AUS + (j)*2048 + wv * 512])
#define STAGE(W, KT)                                                           \
  {                                                                            \
    ST_A(W, 0, KT); ST_A(W, 1, KT); ST_A(W, 2, KT); ST_A(W, 3, KT);            \
    ST_B(W, 0, KT); ST_B(W, 1, KT); ST_B(W, 2, KT); ST_B(W, 3, KT);            \
  }

  // frag read offsets: row*128 + ((ks*64 + (lane>>4)*16) ^ ((row&7)<<4));
  // row&7 == fr&7 for every frag row, so the XOR term is lane-constant.
  const int s_lane = (fr & 7) << 4;
  const int offk0 = ((lane >> 4) * 16) ^ s_lane;
  const int offk1 = (64 + (lane >> 4) * 16) ^ s_lane;
  const int aoffA = (wr + fr) * 128;  // + m*2048 bytes
  int boffB[4];
#pragma unroll
  for (int n = 0; n < 4; ++n)
    boffB[n] = AUS * 2 + (wc + n * 16 + fr) * 128;

  f32x4 acc[4][4];
#pragma unroll
  for (int m = 0; m < 4; ++m)
#pragma unroll
    for (int n = 0; n < 4; ++n) {
      f32x4 z = {0.f, 0.f, 0.f, 0.f};
      acc[m][n] = z;
    }

#define MFMA_(a, b, c) __builtin_amdgcn_mfma_f32_16x16x32_bf16(a, b, c, 0, 0, 0)

#define TILE(Rb, KT)                                                           \
  {                                                                            \
    if ((KT) + 1 < NT) wait_vmcnt<8>(); else wait_vmcnt<0>();                  \
    __builtin_amdgcn_s_barrier();                                              \
    const char* _L = (const char*)Rb;                                          \
    bf16x8 af[4][2], bf[4][2];                                                 \
    _Pragma("unroll") for (int m = 0; m < 4; ++m) {                            \
      af[m][0] = *(const bf16x8*)(_L + aoffA + m * 2048 + offk0);              \
      af[m][1] = *(const bf16x8*)(_L + aoffA + m * 2048 + offk1);              \
    }                                                                          \
    _Pragma("unroll") for (int n = 0; n < 4; ++n) {                            \
      bf[n][0] = *(const bf16x8*)(_L + boffB[n] + offk0);                      \
      bf[n][1] = *(const bf16x8*)(_L + boffB[n] + offk1);                      \
    }                                                                          \
    asm volatile("s_waitcnt lgkmcnt(0)" ::: "memory");                         \
    __builtin_amdgcn_s_barrier(); /* readers done -> buffer free */            \
    if ((KT) + 2 < NT) STAGE(Rb, (KT) + 2);                                    \
    __builtin_amdgcn_s_setprio(1);                                             \
    _Pragma("unroll") for (int ks = 0; ks < 2; ++ks)                           \
      _Pragma("unroll") for (int m = 0; m < 4; ++m)                            \
        _Pragma("unroll") for (int n = 0; n < 4; ++n)                          \
          acc[m][n] = MFMA_(af[m][ks], bf[n][ks], acc[m][n]);                  \
    __builtin_amdgcn_s_setprio(0);                                             \
  }

  const int NT = K >> 6;  // K-tiles (even; 32 or 128)

  // prologue: tile 0 -> lds0, tile 1 -> lds1 (16 loads in flight)
  STAGE(lds0, 0);
  STAGE(lds1, 1);

  for (int kt = 0; kt < NT; kt += 2) {
    TILE(lds0, kt);
    TILE(lds1, kt + 1);
  }

  const int r4 = (lane >> 4) * 4;
#pragma unroll
  for (int m = 0; m < 4; ++m) {
    const int grow = row0 + wr + m * 16 + r4;
#pragma unroll
    for (int n = 0; n < 4; ++n) {
      const int gcol = col0 + wc + n * 16 + fr;
#pragma unroll
      for (int r = 0; r < 4; ++r) {
        const float v = acc[m][n][r];
        const size_t idx = (size_t)(grow + r) * N + gcol;
        if (EPI == 0) {
          Cb[idx] = f2bf(gelu_tanh(v));
        } else {
          Cf[idx] = v + addend[idx];
        }
      }
    }
  }
#undef TILE
#undef MFMA_
#undef STAGE
#undef ST_A
#undef ST_B
}

// ---------------------------------------------------------------------------
extern "C" void kernel_launch(void* const* d_in, const int* in_sizes, int n_in,
                              void* d_out, int out_size, void* d_ws,
                              size_t ws_size, hipStream_t stream) {
  const float* blocks = (const float*)d_in[0];
  const float* partial = (const float*)d_in[1];
  const float* proj_w = (const float*)d_in[2];
  const float* norm_scale = (const float*)d_in[3];
  const float* w1 = (const float*)d_in[4];
  const float* w2 = (const float*)d_in[5];

  float* out = (float*)d_out;
  float* h_out = out;                 // [B,T,D] fp32
  float* new_partial = out + BTD;     // [B,T,D] fp32

  char* ws = (char*)d_ws;
  ushort_t* h_bf = (ushort_t*)ws;                                        // 16 MB
  ushort_t* w1T = (ushort_t*)(ws + (size_t)16777216);                    // 32 MB (F x D)
  ushort_t* w2T = (ushort_t*)(ws + (size_t)16777216 + 33554432);         // 32 MB (D x F)
  ushort_t* act = (ushort_t*)(ws + (size_t)16777216 + 2 * 33554432ull);  // 64 MB (M x F)

  // weight convert + transpose to (N x K) bf16
  transpose_conv<<<dim3(FF / 32, DD / 32), 256, 0, stream>>>(w1, w1T, DD, FF);
  transpose_conv<<<dim3(DD / 32, FF / 32), 256, 0, stream>>>(w2, w2T, FF, DD);

  // fused attention -> h (fp32 out) + h (bf16 for GEMM)
  attn_fuse<<<MM, 256, 0, stream>>>(blocks, partial, proj_w, norm_scale, h_out,
                                    h_bf);

  // FFN: act = gelu(h @ W1) ; new_partial = act @ W2 + partial
  // GEMM1: grid 32x64=2048 blocks; XCD supertile 16x16, macro-grid 2x4.
  gemm128<16, 16, 4, 0><<<(MM / 128) * (FF / 128), 256, 0, stream>>>(
      h_bf, w1T, DD, FF, act, nullptr, nullptr);
  // GEMM2: grid 32x16=512 blocks; XCD supertile 8x8, macro-grid 4x2.
  gemm128<8, 8, 2, 1><<<(MM / 128) * (DD / 128), 256, 0, stream>>>(
      act, w2T, FF, DD, nullptr, partial, new_partial);
}

// Round 7
// 392.655 us; speedup vs baseline: 1.3821x; 1.0029x over previous
//
#include <hip/hip_runtime.h>

typedef unsigned short ushort_t;
typedef __bf16 bf16x8 __attribute__((ext_vector_type(8)));
typedef float f32x4 __attribute__((ext_vector_type(4)));

// sizes (fixed by the problem)
#define NB 8
#define BB 2
#define TT 2048
#define DD 2048
#define FF 8192
#define MM (BB * TT)          // 4096 rows
#define BTD ((size_t)BB * TT * DD)   // 8388608

__device__ __forceinline__ unsigned short f2bf(float f) {
  unsigned int u = __float_as_uint(f);
  u += 0x7FFFu + ((u >> 16) & 1u);
  return (unsigned short)(u >> 16);
}

__device__ __forceinline__ float gelu_tanh(float x) {
  float u = 0.7978845608028654f * (x + 0.044715f * x * x * x);
  float e = __expf(2.0f * u);
  float th = 1.0f - 2.0f / (e + 1.0f);   // robust tanh(u), e=inf -> 1
  return 0.5f * x * (1.0f + th);
}

template <int N>
__device__ __forceinline__ void wait_vmcnt() {
  if constexpr (N == 0) asm volatile("s_waitcnt vmcnt(0)" ::: "memory");
  else if constexpr (N == 3) asm volatile("s_waitcnt vmcnt(3)" ::: "memory");
  else if constexpr (N == 4) asm volatile("s_waitcnt vmcnt(4)" ::: "memory");
  else if constexpr (N == 6) asm volatile("s_waitcnt vmcnt(6)" ::: "memory");
  else if constexpr (N == 8) asm volatile("s_waitcnt vmcnt(8)" ::: "memory");
}

#define ASYNC_COPY16(gp, lp)                                                   \
  __builtin_amdgcn_global_load_lds(                                            \
      (__attribute__((address_space(1))) void*)(gp),                           \
      (__attribute__((address_space(3))) void*)(lp), 16, 0, 0)

// ---------------------------------------------------------------------------
// fp32 (R x C) -> bf16 transposed (C x R)
__global__ __launch_bounds__(256) void transpose_conv(
    const float* __restrict__ in, ushort_t* __restrict__ out, int R, int C) {
  __shared__ float tile[32][33];
  const int tx = threadIdx.x & 31, ty = threadIdx.x >> 5;
  const int r0 = blockIdx.y * 32, c0 = blockIdx.x * 32;
#pragma unroll
  for (int i = 0; i < 32; i += 8)
    tile[ty + i][tx] = in[(size_t)(r0 + ty + i) * C + (c0 + tx)];
  __syncthreads();
#pragma unroll
  for (int i = 0; i < 32; i += 8)
    out[(size_t)(c0 + ty + i) * R + (r0 + tx)] = f2bf(tile[tx][ty + i]);
}

// ---------------------------------------------------------------------------
// Fused block-attention: ONE PASS over V (V rows held in registers).
__global__ __launch_bounds__(256) void attn_fuse(
    const float* __restrict__ blocks, const float* __restrict__ partial,
    const float* __restrict__ proj_w, const float* __restrict__ norm_scale,
    float* __restrict__ h_out, ushort_t* __restrict__ h_bf) {
  const int t = threadIdx.x;
  const int bt = blockIdx.x;
  const size_t rowoff = (size_t)bt * DD;
  const int d0 = t * 4;

  float w[8];
  {
    float4 ns = *(const float4*)(norm_scale + d0);
    float4 pw = *(const float4*)(proj_w + d0);
    w[0] = ns.x * pw.x; w[1] = ns.y * pw.y; w[2] = ns.z * pw.z; w[3] = ns.w * pw.w;
    ns = *(const float4*)(norm_scale + 1024 + d0);
    pw = *(const float4*)(proj_w + 1024 + d0);
    w[4] = ns.x * pw.x; w[5] = ns.y * pw.y; w[6] = ns.z * pw.z; w[7] = ns.w * pw.w;
  }

  float vv[9][8];
  float ss[9], dt[9];
#pragma unroll
  for (int n = 0; n < 9; ++n) {
    const float* rp = (n < 8) ? (blocks + (size_t)n * BTD + rowoff)
                              : (partial + rowoff);
    float4 v0 = *(const float4*)(rp + d0);
    float4 v1 = *(const float4*)(rp + 1024 + d0);
    vv[n][0] = v0.x; vv[n][1] = v0.y; vv[n][2] = v0.z; vv[n][3] = v0.w;
    vv[n][4] = v1.x; vv[n][5] = v1.y; vv[n][6] = v1.z; vv[n][7] = v1.w;
    float a = 0.f, c = 0.f;
#pragma unroll
    for (int j = 0; j < 8; ++j) {
      a += vv[n][j] * vv[n][j];
      c += vv[n][j] * w[j];
    }
    ss[n] = a; dt[n] = c;
  }

  __shared__ float red[2][9][4];
  const int lane = t & 63, wv = t >> 6;
#pragma unroll
  for (int n = 0; n < 9; ++n) {
    float a = ss[n], c = dt[n];
#pragma unroll
    for (int off = 32; off > 0; off >>= 1) {
      a += __shfl_down(a, off, 64);
      c += __shfl_down(c, off, 64);
    }
    if (lane == 0) { red[0][n][wv] = a; red[1][n][wv] = c; }
  }
  __syncthreads();
  __shared__ float logit_s[9];
  if (t < 9) {
    float a = red[0][t][0] + red[0][t][1] + red[0][t][2] + red[0][t][3];
    float c = red[1][t][0] + red[1][t][1] + red[1][t][2] + red[1][t][3];
    logit_s[t] = c * rsqrtf(a * (1.0f / (float)DD) + 1e-8f);
  }
  __syncthreads();

  float lg[9], mx = -1e30f;
#pragma unroll
  for (int n = 0; n < 9; ++n) { lg[n] = logit_s[n]; mx = fmaxf(mx, lg[n]); }
  float den = 0.0f;
#pragma unroll
  for (int n = 0; n < 9; ++n) { lg[n] = __expf(lg[n] - mx); den += lg[n]; }
  const float inv = 1.0f / den;

  float h[8] = {0, 0, 0, 0, 0, 0, 0, 0};
#pragma unroll
  for (int n = 0; n < 9; ++n) {
    const float a = lg[n] * inv;
#pragma unroll
    for (int j = 0; j < 8; ++j) h[j] += a * vv[n][j];
  }

  float4 o0 = {h[0], h[1], h[2], h[3]}, o1 = {h[4], h[5], h[6], h[7]};
  *(float4*)(h_out + rowoff + d0) = o0;
  *(float4*)(h_out + rowoff + 1024 + d0) = o1;
  uint2 p0, p1;
  p0.x = (unsigned)f2bf(h[0]) | ((unsigned)f2bf(h[1]) << 16);
  p0.y = (unsigned)f2bf(h[2]) | ((unsigned)f2bf(h[3]) << 16);
  p1.x = (unsigned)f2bf(h[4]) | ((unsigned)f2bf(h[5]) << 16);
  p1.y = (unsigned)f2bf(h[6]) | ((unsigned)f2bf(h[7]) << 16);
  *(uint2*)(h_bf + rowoff + d0) = p0;
  *(uint2*)(h_bf + rowoff + 1024 + d0) = p1;
}

// ---------------------------------------------------------------------------
// Quad-ring bf16 GEMM: BM=256, BK=32 sub-tiles, 4 rotating LDS buffers,
// ONE barrier per sub-tile. 8 waves (WM x WN), per-wave tile
// (256/WM) x (BN/WN). Schedule per sub-tile t:
//   wait vmcnt(L*min(2,NT-1-t))  // tile t landed; t+1,t+2 in flight
//   s_barrier                    // t visible to all; readers of t-1 done
//   stage(t+3) -> buf[(t+3)&3]   // == buf[(t-1)&3], race-free by barrier
//   ds_read 12|8 frags; 32|16 MFMA (compiler-placed partial lgkm waits)
// Waves de-phase inside the ~1100-cyc barrier interval: one wave reads LDS
// while another runs MFMA -> both pipes fed (vs lockstep alternation that
// pinned MfmaUtil at 33-38% in R2-R6).
// LDS layout (BK=32 => 64-B rows are swizzle-hostile): rowpair-packed
// A[rp][ (r&1)*64 + k*2 ] with inner16B-slot XOR ((rp&7)<<4) — involution;
// staged via pre-swizzled global source; frag reads conflict-free (8 lanes
// per rp-row hit all 8 slots exactly once).
// EPI=0: C = gelu(A@B) -> bf16.  EPI=1: C = A@B + addend -> fp32.
template <int BN, int WM, int WN, int SBY, int SBX, int MCX, int EPI>
__global__ __launch_bounds__(512, 2) void gemmQ(
    const ushort_t* __restrict__ A, const ushort_t* __restrict__ BT,
    const int K, const int N, ushort_t* __restrict__ Cb,
    const float* __restrict__ addend, float* __restrict__ Cf) {
  constexpr int MFR = 256 / WM / 16;   // m-frags per wave
  constexpr int NFR = BN / WN / 16;    // n-frags per wave
  constexpr int AS = 16384;            // A sub-tile bytes (256 x 32 x 2B)
  constexpr int BS = BN * 64;          // B sub-tile bytes
  constexpr int RS = AS + BS;          // ring stride
  constexpr int LB = BS / 8192;        // B loads/thread (2 | 1)
  constexpr int LT = 2 + LB;           // loads/thread/sub-tile

  __shared__ __align__(16) char lds[4 * RS];

  const int t = threadIdx.x;
  const int lane = t & 63, wv = t >> 6;
  const int fr = lane & 15, kslot = lane >> 4;
  const int WRow = (wv / WN) * (256 / WM);
  const int WCol = (wv % WN) * (BN / WN);

  // 2D XCD supertile
  const int wg = blockIdx.x;
  const int xcd = wg & 7, local = wg >> 3;
  const int by = (xcd / MCX) * SBY + local / SBX;
  const int bx = (xcd % MCX) * SBX + local % SBX;
  const int row0 = by * 256, col0 = bx * BN;

  // staging sources: thread covers LDS bytes o = j*8192 + t*16 (linear dest);
  // global element = inverse of the rowpair+XOR layout.
  const ushort_t* ga[2];
  const ushort_t* gb[LB];
#pragma unroll
  for (int j = 0; j < 2; ++j) {
    const int o = j * 8192 + t * 16;
    const int rp = o >> 7;
    const int iX = (o & 127) ^ ((rp & 7) << 4);
    ga[j] = A + (size_t)(row0 + rp * 2 + (iX >> 6)) * K + ((iX & 63) >> 1);
  }
#pragma unroll
  for (int j = 0; j < LB; ++j) {
    const int o = j * 8192 + t * 16;
    const int rp = o >> 7;
    const int iX = (o & 127) ^ ((rp & 7) << 4);
    gb[j] = BT + (size_t)(col0 + rp * 2 + (iX >> 6)) * K + ((iX & 63) >> 1);
  }

#define STAGE(QQ, KT)                                                          \
  {                                                                            \
    ASYNC_COPY16(ga[0] + (size_t)(KT) * 32, lds + (QQ)*RS + t * 16);           \
    ASYNC_COPY16(ga[1] + (size_t)(KT) * 32, lds + (QQ)*RS + 8192 + t * 16);    \
    ASYNC_COPY16(gb[0] + (size_t)(KT) * 32, lds + (QQ)*RS + AS + t * 16);      \
    if constexpr (LB == 2)                                                     \
      ASYNC_COPY16(gb[1] + (size_t)(KT) * 32,                                  \
                   lds + (QQ)*RS + AS + 8192 + t * 16);                        \
  }

  // fragment read offsets: row r = W{Row,Col}+m*16+fr, k = kslot*8..+8:
  // byte = (r>>1)*128 + ((((r&1)<<6)|(kslot<<4)) ^ (((r>>1)&7)<<4));
  // rp&7 is m-independent (m*16 rows = m*8 rowpairs, multiple of 8).
  const int arp0 = (WRow + fr) >> 1;
  const int aoff =
      arp0 * 128 + (((((fr & 1) << 6) | (kslot << 4))) ^ ((arp0 & 7) << 4));
  const int brp0 = (WCol + fr) >> 1;
  const int boff = AS + brp0 * 128 +
                   (((((fr & 1) << 6) | (kslot << 4))) ^ ((brp0 & 7) << 4));

  f32x4 acc[MFR][NFR];
#pragma unroll
  for (int m = 0; m < MFR; ++m)
#pragma unroll
    for (int n = 0; n < NFR; ++n) {
      f32x4 z = {0.f, 0.f, 0.f, 0.f};
      acc[m][n] = z;
    }

#define MFMA_(a, b, c) __builtin_amdgcn_mfma_f32_16x16x32_bf16(a, b, c, 0, 0, 0)

  const int NT = K >> 5;  // sub-tiles of K=32 (64 or 256; multiple of 4)

  STAGE(0, 0);
  STAGE(1, 1);
  STAGE(2, 2);

  for (int t0 = 0; t0 < NT; t0 += 4) {
#pragma unroll
    for (int q = 0; q < 4; ++q) {
      const int kt = t0 + q;
      const int rem = NT - 1 - kt;
      if (rem >= 2) wait_vmcnt<2 * LT>();
      else if (rem == 1) wait_vmcnt<LT>();
      else wait_vmcnt<0>();
      __builtin_amdgcn_s_barrier();
      if (kt + 3 < NT) STAGE((q + 3) & 3, kt + 3);
      const char* Lq = lds + q * RS;
      bf16x8 af[MFR], bfv[NFR];
#pragma unroll
      for (int m = 0; m < MFR; ++m)
        af[m] = *(const bf16x8*)(Lq + aoff + m * 1024);
#pragma unroll
      for (int n = 0; n < NFR; ++n)
        bfv[n] = *(const bf16x8*)(Lq + boff + n * 1024);
      __builtin_amdgcn_s_setprio(1);
#pragma unroll
      for (int m = 0; m < MFR; ++m)
#pragma unroll
        for (int n = 0; n < NFR; ++n)
          acc[m][n] = MFMA_(af[m], bfv[n], acc[m][n]);
      __builtin_amdgcn_s_setprio(0);
    }
  }

  const int r4 = kslot * 4;
#pragma unroll
  for (int m = 0; m < MFR; ++m) {
    const int grow = row0 + WRow + m * 16 + r4;
#pragma unroll
    for (int n = 0; n < NFR; ++n) {
      const int gcol = col0 + WCol + n * 16 + fr;
#pragma unroll
      for (int r = 0; r < 4; ++r) {
        const float v = acc[m][n][r];
        const size_t idx = (size_t)(grow + r) * N + gcol;
        if (EPI == 0) {
          Cb[idx] = f2bf(gelu_tanh(v));
        } else {
          Cf[idx] = v + addend[idx];
        }
      }
    }
  }
#undef MFMA_
#undef STAGE
}

// ---------------------------------------------------------------------------
extern "C" void kernel_launch(void* const* d_in, const int* in_sizes, int n_in,
                              void* d_out, int out_size, void* d_ws,
                              size_t ws_size, hipStream_t stream) {
  const float* blocks = (const float*)d_in[0];
  const float* partial = (const float*)d_in[1];
  const float* proj_w = (const float*)d_in[2];
  const float* norm_scale = (const float*)d_in[3];
  const float* w1 = (const float*)d_in[4];
  const float* w2 = (const float*)d_in[5];

  float* out = (float*)d_out;
  float* h_out = out;                 // [B,T,D] fp32
  float* new_partial = out + BTD;     // [B,T,D] fp32

  char* ws = (char*)d_ws;
  ushort_t* h_bf = (ushort_t*)ws;                                        // 16 MB
  ushort_t* w1T = (ushort_t*)(ws + (size_t)16777216);                    // 32 MB (F x D)
  ushort_t* w2T = (ushort_t*)(ws + (size_t)16777216 + 33554432);         // 32 MB (D x F)
  ushort_t* act = (ushort_t*)(ws + (size_t)16777216 + 2 * 33554432ull);  // 64 MB (M x F)

  // weight convert + transpose to (N x K) bf16
  transpose_conv<<<dim3(FF / 32, DD / 32), 256, 0, stream>>>(w1, w1T, DD, FF);
  transpose_conv<<<dim3(DD / 32, FF / 32), 256, 0, stream>>>(w2, w2T, FF, DD);

  // fused attention -> h (fp32 out) + h (bf16 for GEMM)
  attn_fuse<<<MM, 256, 0, stream>>>(blocks, partial, proj_w, norm_scale, h_out,
                                    h_bf);

  // FFN: act = gelu(h @ W1) ; new_partial = act @ W2 + partial
  // GEMM1: 256x256 tile, waves 2Mx4N (wave 128x64), grid 16x32=512,
  //        supertile 8x8 per XCD (macro 2x4).
  gemmQ<256, 2, 4, 8, 8, 4, 0><<<512, 512, 0, stream>>>(
      h_bf, w1T, DD, FF, act, nullptr, nullptr);
  // GEMM2: 256x128 tile, waves 4Mx2N (wave 64x64), grid 16x16=256,
  //        supertile 4x8 per XCD (macro 4x2).
  gemmQ<128, 4, 2, 4, 8, 2, 1><<<256, 512, 0, stream>>>(
      act, w2T, FF, DD, nullptr, partial, new_partial);
}